// Round 3
// baseline (2253.920 us; speedup 1.0000x reference)
//
#include <hip/hip_runtime.h>

#define NPTS   65536
#define NBATCH 8
#define TSIZE  131072
#define TM1    (TSIZE - 1)
#define CAP    8192     // pairs per (b,ko) bucket
#define PPB    64       // pairs per conv_off chunk
#define CPB    4        // chunks per conv_off block
#define BMW    65536    // bitmap words per batch (2^21 bits)
#define STG    64       // LDS staging slots per bucket in build_pairs
#define PCS    16       // paircnt stride in ints (one 64B line per counter)

__device__ __forceinline__ unsigned hashf(int code) {
    unsigned u = (unsigned)code * 2654435761u;
    return (u >> 13) & TM1;
}

// ---------- init origin bits to +inf ----------
__global__ void init_origin(int* ob) {
    if (threadIdx.x < 3) ob[threadIdx.x] = 0x7F800000; // +inf
}

// ---------- global per-component min of xyz ----------
__global__ void minred(const float* __restrict__ xyz, int* __restrict__ ob) {
    int tid = threadIdx.x;
    float mx = INFINITY, my = INFINITY, mz = INFINITY;
    size_t total = (size_t)NBATCH * NPTS;
    for (size_t i = (size_t)blockIdx.x * blockDim.x + tid; i < total;
         i += (size_t)gridDim.x * blockDim.x) {
        mx = fminf(mx, xyz[i * 3 + 0]);
        my = fminf(my, xyz[i * 3 + 1]);
        mz = fminf(mz, xyz[i * 3 + 2]);
    }
    __shared__ float sx[256], sy[256], sz[256];
    sx[tid] = mx; sy[tid] = my; sz[tid] = mz;
    __syncthreads();
    for (int s = 128; s > 0; s >>= 1) {
        if (tid < s) {
            sx[tid] = fminf(sx[tid], sx[tid + s]);
            sy[tid] = fminf(sy[tid], sy[tid + s]);
            sz[tid] = fminf(sz[tid], sz[tid + s]);
        }
        __syncthreads();
    }
    if (tid == 0) {
        // coords >= 0 so signed-int compare of float bits preserves order
        atomicMin(&ob[0], __float_as_int(sx[0]));
        atomicMin(&ob[1], __float_as_int(sy[0]));
        atomicMin(&ob[2], __float_as_int(sz[0]));
    }
}

// ---------- voxel codes per point + hash insert + per-slot point count ----------
__global__ void build_codes(const float* __restrict__ xyz, const int* __restrict__ ob,
                            int* __restrict__ pslot, int* __restrict__ hashk,
                            int* __restrict__ scnt) {
    int b = blockIdx.y;
    int p = blockIdx.x * blockDim.x + threadIdx.x;
    size_t gi = (size_t)b * NPTS + p;
    float ox = __int_as_float(ob[0]);
    float oy = __int_as_float(ob[1]);
    float oz = __int_as_float(ob[2]);
    float x = xyz[gi * 3 + 0], y = xyz[gi * 3 + 1], z = xyz[gi * 3 + 2];
    int vx = (int)((x - ox) / 0.4f); if (vx < 0) vx = 0;
    int vy = (int)((y - oy) / 0.4f); if (vy < 0) vy = 0;
    int vz = (int)((z - oz) / 0.4f); if (vz < 0) vz = 0;
    int code = vx | (vy << 7) | (vz << 14);
    int* hk = hashk + (size_t)b * TSIZE;
    unsigned s = hashf(code);
    while (true) {
        int prev = atomicCAS(&hk[s], -1, code);
        if (prev == -1 || prev == code) break;
        s = (s + 1) & TM1;
    }
    pslot[gi] = (int)s;
    atomicAdd(&scnt[(size_t)b * TSIZE + s], 1);
}

// ---------- assign voxel ids to occupied hash slots + bitmap + per-voxel npts ----------
__global__ void assign_ids(const int* __restrict__ hashk, int* __restrict__ hashv,
                           int* __restrict__ nvox, int* __restrict__ voxcode,
                           unsigned* __restrict__ bitmap, const int* __restrict__ scnt,
                           int* __restrict__ vnpts) {
    int b = blockIdx.y;
    int s = blockIdx.x * blockDim.x + threadIdx.x;
    int k = hashk[(size_t)b * TSIZE + s];
    if (k != -1) {
        int id = atomicAdd(&nvox[b], 1);
        hashv[(size_t)b * TSIZE + s] = id;
        voxcode[(size_t)b * NPTS + id] = k;
        vnpts[(size_t)b * NPTS + id] = scnt[(size_t)b * TSIZE + s];
        atomicOr(&bitmap[(size_t)b * BMW + (k >> 5)], 1u << (k & 31));
    }
}

// ---------- per-point: record inv; single-point voxels store vfeat directly ----------
__global__ void point_pass(const int* __restrict__ pslot, const int* __restrict__ scnt,
                           const int* __restrict__ hashv, const float* __restrict__ feat,
                           const float* __restrict__ mask, int* __restrict__ inv,
                           float* __restrict__ cntf, float* __restrict__ fsum) {
    int b = blockIdx.y;
    int p = blockIdx.x * blockDim.x + threadIdx.x;
    size_t gi = (size_t)b * NPTS + p;
    int s = pslot[gi];
    int v = hashv[(size_t)b * TSIZE + s];
    inv[gi] = v;
    int n = scnt[(size_t)b * TSIZE + s];
    float m = mask[gi];
    const float4* f4 = (const float4*)(feat + gi * 16);
    float4 f0 = f4[0], f1 = f4[1], f2 = f4[2], f3 = f4[3];
    float* fs = fsum + ((size_t)b * NPTS + v) * 16;
    if (n == 1) {
        float4 o0 = {f0.x * m, f0.y * m, f0.z * m, f0.w * m};
        float4 o1 = {f1.x * m, f1.y * m, f1.z * m, f1.w * m};
        float4 o2 = {f2.x * m, f2.y * m, f2.z * m, f2.w * m};
        float4 o3 = {f3.x * m, f3.y * m, f3.z * m, f3.w * m};
        float4* fs4 = (float4*)fs;
        fs4[0] = o0; fs4[1] = o1; fs4[2] = o2; fs4[3] = o3;
    } else {
        atomicAdd(&cntf[(size_t)b * NPTS + v], m);
        atomicAdd(&fs[0],  f0.x * m); atomicAdd(&fs[1],  f0.y * m);
        atomicAdd(&fs[2],  f0.z * m); atomicAdd(&fs[3],  f0.w * m);
        atomicAdd(&fs[4],  f1.x * m); atomicAdd(&fs[5],  f1.y * m);
        atomicAdd(&fs[6],  f1.z * m); atomicAdd(&fs[7],  f1.w * m);
        atomicAdd(&fs[8],  f2.x * m); atomicAdd(&fs[9],  f2.y * m);
        atomicAdd(&fs[10], f2.z * m); atomicAdd(&fs[11], f2.w * m);
        atomicAdd(&fs[12], f3.x * m); atomicAdd(&fs[13], f3.y * m);
        atomicAdd(&fs[14], f3.z * m); atomicAdd(&fs[15], f3.w * m);
    }
}

// ---------- finish multi-point voxels: vfeat = fsum / max(cnt,1) ----------
__global__ void vfeat_div(float* __restrict__ fsum, const float* __restrict__ cntf,
                          const int* __restrict__ vnpts, const int* __restrict__ nvox) {
    int b = blockIdx.y;
    int v = blockIdx.x * blockDim.x + threadIdx.x;
    if (v >= nvox[b]) return;
    if (vnpts[(size_t)b * NPTS + v] <= 1) return;
    float cn = fmaxf(cntf[(size_t)b * NPTS + v], 1.0f);
    float* fs = fsum + ((size_t)b * NPTS + v) * 16;
    #pragma unroll
    for (int c = 0; c < 16; c++) fs[c] /= cn;
}

// ---------- build off-center rulebook (bitmap-probed, LDS-aggregated) ----------
__global__ __launch_bounds__(256) void build_pairs(
    const int* __restrict__ hashk, const int* __restrict__ hashv,
    const int* __restrict__ voxcode, const int* __restrict__ nvox,
    const unsigned* __restrict__ bitmap,
    unsigned* __restrict__ pairs, int* __restrict__ paircnt) {
    int b = blockIdx.y;
    int t = threadIdx.x;
    int v = blockIdx.x * 256 + t;
    __shared__ int lcnt[32];
    __shared__ int lbase[32];
    __shared__ unsigned s_pay[27 * STG];
    if (t < 32) lcnt[t] = 0;
    __syncthreads();

    bool active = (v < nvox[b]);
    int code = 0;
    if (active) code = voxcode[(size_t)b * NPTS + v];
    int x = code & 127, y = (code >> 7) & 127, z = code >> 14;
    const unsigned* bm = bitmap + (size_t)b * BMW;
    const int* hk = hashk + (size_t)b * TSIZE;
    const int* hv = hashv + (size_t)b * TSIZE;

    // phase A: 13 independent bitmap loads -> hitmask
    int ncode[13];
    unsigned hitmask = 0;
    #pragma unroll
    for (int d = 0; d < 13; d++) {
        int dz = d / 9 - 1, r9 = d % 9;
        int dy = r9 / 3 - 1, dx = r9 % 3 - 1;
        int nx = x + dx, ny = y + dy, nz = z + dz;
        bool inb = active && ((unsigned)nx <= 127u) && ((unsigned)ny <= 127u) &&
                   ((unsigned)nz <= 127u);
        int nc = nx | (ny << 7) | (nz << 14);
        ncode[d] = nc;
        unsigned w = 0;
        if (inb) w = bm[nc >> 5];
        if (inb && ((w >> (nc & 31)) & 1u)) hitmask |= 1u << d;
    }

    // phase B: resolve ids for hits, stage pair emissions in LDS
    #pragma unroll
    for (int d = 0; d < 13; d++) {
        if (hitmask & (1u << d)) {
            int nc = ncode[d];
            unsigned s = hashf(nc);
            int nb = -1;
            while (true) {
                int k = hk[s];
                if (k == nc) { nb = hv[s]; break; }
                if (k == -1) break;  // safety; bitmap==hash by construction
                s = (s + 1) & TM1;
            }
            if (nb >= 0) {
                unsigned p1 = ((unsigned)v << 16) | (unsigned)nb;
                unsigned p2 = ((unsigned)nb << 16) | (unsigned)v;
                int l1 = atomicAdd(&lcnt[d], 1);
                if (l1 < STG) {
                    s_pay[d * STG + l1] = p1;
                } else {  // rare overflow: direct global slot (disjoint from bulk)
                    int gs = atomicAdd(&paircnt[(b * 27 + d) * PCS], 1);
                    if (gs < CAP) pairs[(size_t)(b * 27 + d) * CAP + gs] = p1;
                }
                int k2 = 26 - d;
                int l2 = atomicAdd(&lcnt[k2], 1);
                if (l2 < STG) {
                    s_pay[k2 * STG + l2] = p2;
                } else {
                    int gs = atomicAdd(&paircnt[(b * 27 + k2) * PCS], 1);
                    if (gs < CAP) pairs[(size_t)(b * 27 + k2) * CAP + gs] = p2;
                }
            }
        }
    }
    __syncthreads();

    if (t < 27) {
        int n = lcnt[t]; if (n > STG) n = STG;
        lbase[t] = (n > 0) ? atomicAdd(&paircnt[(b * 27 + t) * PCS], n) : 0;
    }
    __syncthreads();

    for (int k = t; k < 27 * STG; k += 256) {
        int bkt = k / STG, i = k % STG;
        int n = lcnt[bkt]; if (n > STG) n = STG;
        if (i < n) {
            int gs = lbase[bkt] + i;
            if (gs < CAP) pairs[(size_t)(b * 27 + bkt) * CAP + gs] = s_pay[k];
        }
    }
}

// ---------- dense center GEMM (Cout split into COLS slices; swizzled A_s) ----------
// A_s bank swizzle: element (ci, r) stored at [ci][r ^ (ci & 28)]. Transpose-store
// lanes then hit max 2-way conflicts (free) instead of 8-way; MAC-phase reads are
// wave-uniform broadcasts and float4 alignment is preserved (swizzle is a mult of 4).
template <int Cin, int Cout, int COLS, bool XFORM>
__global__ __launch_bounds__(256) void conv_center(
    const float* __restrict__ in, float* __restrict__ outp,
    const float* __restrict__ W13, const float* __restrict__ bias,
    const float* __restrict__ sc, const float* __restrict__ sh,
    const int* __restrict__ nvox) {
    constexpr int BR  = 64;
    constexpr int CT  = COLS;
    constexpr int RG  = 256 / CT;
    constexpr int RPT = BR / RG;
    int b = blockIdx.y;
    int nv = nvox[b];
    int v0 = blockIdx.x * BR;
    if (v0 >= nv) return;
    int colofs = blockIdx.z * COLS;
    __shared__ __align__(16) float A_s[Cin][BR + 4];
    __shared__ __align__(16) float W_s[Cin * COLS];
    int t = threadIdx.x;
    for (int i4 = t; i4 < Cin * COLS / 4; i4 += 256) {
        int lin = i4 * 4;
        int ci = lin / COLS, cc = lin % COLS;
        *(float4*)&W_s[lin] = *(const float4*)&W13[(size_t)ci * Cout + colofs + cc];
    }
    const float* inb = in + (size_t)b * NPTS * Cin;
    for (int i4 = t; i4 < BR * Cin / 4; i4 += 256) {
        int lin = i4 * 4;
        int r = lin / Cin, ci = lin % Cin;
        float4 val = *(const float4*)&inb[(size_t)(v0 + r) * Cin + ci];
        if (XFORM) {
            val.x = fmaxf(val.x * sc[ci + 0] + sh[ci + 0], 0.0f);
            val.y = fmaxf(val.y * sc[ci + 1] + sh[ci + 1], 0.0f);
            val.z = fmaxf(val.z * sc[ci + 2] + sh[ci + 2], 0.0f);
            val.w = fmaxf(val.w * sc[ci + 3] + sh[ci + 3], 0.0f);
        }
        A_s[ci + 0][r ^ ((ci + 0) & 28)] = val.x;
        A_s[ci + 1][r ^ ((ci + 1) & 28)] = val.y;
        A_s[ci + 2][r ^ ((ci + 2) & 28)] = val.z;
        A_s[ci + 3][r ^ ((ci + 3) & 28)] = val.w;
    }
    __syncthreads();
    int c = t % CT;
    int r0 = (t / CT) * RPT;
    float acc[RPT];
    #pragma unroll
    for (int r = 0; r < RPT; r++) acc[r] = 0.0f;
    #pragma unroll 4
    for (int ci = 0; ci < Cin; ci++) {
        int sw = ci & 28;
        float w = W_s[ci * COLS + c];
        #pragma unroll
        for (int k = 0; k < RPT / 4; k++) {
            float4 a4 = *(const float4*)&A_s[ci][(r0 + 4 * k) ^ sw];
            acc[4 * k + 0] += a4.x * w;
            acc[4 * k + 1] += a4.y * w;
            acc[4 * k + 2] += a4.z * w;
            acc[4 * k + 3] += a4.w * w;
        }
    }
    float* ob = outp + (size_t)b * NPTS * Cout;
    float bs = bias[colofs + c];
    #pragma unroll
    for (int r = 0; r < RPT; r++) {
        int row = v0 + r0 + r;
        if (row < nv)
            ob[(size_t)row * Cout + colofs + c] = acc[r] + bs;
    }
}

// ---------- off-center: chunked persistent blocks + reg-prefetch + swizzled A_s ----------
// Each block owns CPB chunks of PPB pairs from one (b,ko) bucket: W slice and the
// pair list are loaded ONCE; while chunk k's MAC runs, chunk k+1's gather rows sit
// in flight in registers (T14 async-stage split) so the random-row HBM/L2 latency
// hides under the FMAs instead of stalling at the barrier.
template <int Cin, int Cout, int COLS, bool XFORM>
__global__ __launch_bounds__(256) void conv_off(
    const float* __restrict__ in, float* __restrict__ outp,
    const float* __restrict__ W, const float* __restrict__ sc,
    const float* __restrict__ sh, const unsigned* __restrict__ pairs,
    const int* __restrict__ paircnt) {
    constexpr int BR  = PPB;
    constexpr int CT  = COLS;
    constexpr int RG  = 256 / CT;
    constexpr int RPT = BR / RG;
    constexpr int NQ  = BR * Cin / (4 * 256);   // float4 gathers per thread per chunk
    int bk = blockIdx.y;            // b*27 + ko
    int ko = bk % 27;
    int b  = bk / 27;
    int cnt = paircnt[bk * PCS];
    if (cnt > CAP) cnt = CAP;
    int base = blockIdx.x * (BR * CPB);
    if (base >= cnt) return;
    int colofs = blockIdx.z * COLS;
    __shared__ __align__(16) float A_s[Cin][BR + 4];
    __shared__ __align__(16) float W_s[Cin * COLS];
    __shared__ unsigned pr_s[BR * CPB];
    int t = threadIdx.x;
    const float* Wk = W + (size_t)ko * Cin * Cout;
    for (int i4 = t; i4 < Cin * COLS / 4; i4 += 256) {
        int lin = i4 * 4;
        int ci = lin / COLS, cc = lin % COLS;
        *(float4*)&W_s[lin] = *(const float4*)&Wk[(size_t)ci * Cout + colofs + cc];
    }
    const unsigned* pb = pairs + (size_t)bk * CAP;
    for (int i = t; i < BR * CPB; i += 256)
        pr_s[i] = (base + i < cnt) ? pb[base + i] : 0u;
    __syncthreads();

    const float* inb = in + (size_t)b * NPTS * Cin;
    float* ob = outp + (size_t)b * NPTS * Cout;
    int c = t % CT;
    int r0 = (t / CT) * RPT;

    int rr[NQ], cch[NQ];
    #pragma unroll
    for (int q = 0; q < NQ; q++) {
        int lin = (t + q * 256) * 4;
        rr[q]  = lin / Cin;
        cch[q] = lin % Cin;
    }
    // prologue: gather chunk 0 into regs
    float4 stg[NQ];
    #pragma unroll
    for (int q = 0; q < NQ; q++) {
        int vin = (int)(pr_s[rr[q]] & 0xffffu);
        stg[q] = *(const float4*)&inb[(size_t)vin * Cin + cch[q]];
    }

    int nchunk = (cnt - base + BR - 1) / BR;
    if (nchunk > CPB) nchunk = CPB;
    for (int ch = 0; ch < nchunk; ch++) {
        // staged regs -> A_s (XFORM + swizzle)
        #pragma unroll
        for (int q = 0; q < NQ; q++) {
            float4 val = stg[q];
            int ci = cch[q], r = rr[q];
            if (XFORM) {
                val.x = fmaxf(val.x * sc[ci + 0] + sh[ci + 0], 0.0f);
                val.y = fmaxf(val.y * sc[ci + 1] + sh[ci + 1], 0.0f);
                val.z = fmaxf(val.z * sc[ci + 2] + sh[ci + 2], 0.0f);
                val.w = fmaxf(val.w * sc[ci + 3] + sh[ci + 3], 0.0f);
            }
            A_s[ci + 0][r ^ ((ci + 0) & 28)] = val.x;
            A_s[ci + 1][r ^ ((ci + 1) & 28)] = val.y;
            A_s[ci + 2][r ^ ((ci + 2) & 28)] = val.z;
            A_s[ci + 3][r ^ ((ci + 3) & 28)] = val.w;
        }
        __syncthreads();
        // prefetch next chunk's rows (in flight during MAC)
        if (ch + 1 < nchunk) {
            #pragma unroll
            for (int q = 0; q < NQ; q++) {
                int vin = (int)(pr_s[(ch + 1) * BR + rr[q]] & 0xffffu);
                stg[q] = *(const float4*)&inb[(size_t)vin * Cin + cch[q]];
            }
        }
        // MAC
        float acc[RPT];
        #pragma unroll
        for (int r = 0; r < RPT; r++) acc[r] = 0.0f;
        #pragma unroll 4
        for (int ci = 0; ci < Cin; ci++) {
            int sw = ci & 28;
            float w = W_s[ci * COLS + c];
            #pragma unroll
            for (int k = 0; k < RPT / 4; k++) {
                float4 a4 = *(const float4*)&A_s[ci][(r0 + 4 * k) ^ sw];
                acc[4 * k + 0] += a4.x * w;
                acc[4 * k + 1] += a4.y * w;
                acc[4 * k + 2] += a4.z * w;
                acc[4 * k + 3] += a4.w * w;
            }
        }
        int nAct = cnt - (base + ch * BR);
        if (nAct > BR) nAct = BR;
        #pragma unroll
        for (int r = 0; r < RPT; r++) {
            if (r0 + r < nAct) {
                int vout = (int)(pr_s[ch * BR + r0 + r] >> 16);
                atomicAdd(&ob[(size_t)vout * Cout + colofs + c], acc[r]);
            }
        }
        __syncthreads();
    }
}

// ---------- BN stats: per-channel sum and sumsq over valid voxels ----------
template <int C>
__global__ void bn_stats(const float* __restrict__ h, const int* __restrict__ nvox,
                         float* __restrict__ sums) {
    constexpr int RPB = 256 / C;
    int b = blockIdx.y;
    int nv = nvox[b];
    int tid = threadIdx.x;
    int c = tid % C;
    int r = tid / C;
    float s0 = 0.0f, s1 = 0.0f;
    for (int v = blockIdx.x * RPB + r; v < nv; v += gridDim.x * RPB) {
        float x = h[((size_t)b * NPTS + v) * C + c];
        s0 += x;
        s1 += x * x;
    }
    __shared__ float l0[256], l1[256];
    l0[tid] = s0; l1[tid] = s1;
    __syncthreads();
    for (int s = 128; s >= C; s >>= 1) {
        if (tid < s) { l0[tid] += l0[tid + s]; l1[tid] += l1[tid + s]; }
        __syncthreads();
    }
    if (tid < C) {
        atomicAdd(&sums[c], l0[tid]);
        atomicAdd(&sums[C + c], l1[tid]);
    }
}

template <int C>
__global__ void bn_finalize(const float* __restrict__ sums, const int* __restrict__ nvox,
                            const float* __restrict__ g, const float* __restrict__ be,
                            float* __restrict__ scale, float* __restrict__ shift) {
    int c = threadIdx.x;
    if (c >= C) return;
    float n = 0.0f;
    for (int b = 0; b < NBATCH; b++) n += (float)nvox[b];
    n = fmaxf(n, 1.0f);
    float mean = sums[c] / n;
    float var = sums[C + c] / n - mean * mean;
    float a = g[c] * rsqrtf(var + 1e-5f);
    scale[c] = a;
    shift[c] = be[c] - mean * a;
}

// ---------- fused BN3 + ReLU + gather to points + mask ----------
__global__ void out_gather(const float* __restrict__ h3, const int* __restrict__ inv,
                           const float* __restrict__ mask, const float* __restrict__ sc,
                           const float* __restrict__ sh, float* __restrict__ out) {
    int b = blockIdx.y;
    size_t i = (size_t)blockIdx.x * blockDim.x + threadIdx.x; // over NPTS*128
    int p = (int)(i >> 7);
    int c = (int)(i & 127);
    size_t gi = (size_t)b * NPTS + p;
    int v = inv[gi];
    float m = mask[gi];
    float x = h3[((size_t)b * NPTS + v) * 128 + c];
    x = fmaxf(x * sc[c] + sh[c], 0.0f);
    out[gi * 128 + c] = x * m;
}

extern "C" void kernel_launch(void* const* d_in, const int* in_sizes, int n_in,
                              void* d_out, int out_size, void* d_ws, size_t ws_size,
                              hipStream_t stream) {
    const float* xyz  = (const float*)d_in[0];
    const float* feat = (const float*)d_in[1];
    const float* mask = (const float*)d_in[2];
    const float* W1 = (const float*)d_in[3];
    const float* b1 = (const float*)d_in[4];
    const float* g1 = (const float*)d_in[5];
    const float* be1 = (const float*)d_in[6];
    const float* W2 = (const float*)d_in[7];
    const float* b2 = (const float*)d_in[8];
    const float* g2 = (const float*)d_in[9];
    const float* be2 = (const float*)d_in[10];
    const float* W3 = (const float*)d_in[11];
    const float* b3 = (const float*)d_in[12];
    const float* g3 = (const float*)d_in[13];
    const float* be3 = (const float*)d_in[14];
    float* out = (float*)d_out;

    char* ws = (char*)d_ws;
    size_t off = 0;
    auto alloc = [&](size_t bytes) {
        void* p = ws + off;
        off += (bytes + 255) & ~(size_t)255;
        return p;
    };
    int*      hashk   = (int*)alloc((size_t)NBATCH * TSIZE * 4);
    int*      hashv   = (int*)alloc((size_t)NBATCH * TSIZE * 4);
    int*      scnt    = (int*)alloc((size_t)NBATCH * TSIZE * 4);
    int*      nvox    = (int*)alloc(NBATCH * 4);
    int*      origin  = (int*)alloc(16);
    int*      pslot   = (int*)alloc((size_t)NBATCH * NPTS * 4);
    int*      voxcode = (int*)alloc((size_t)NBATCH * NPTS * 4);
    int*      vnpts   = (int*)alloc((size_t)NBATCH * NPTS * 4);
    int*      inv     = (int*)alloc((size_t)NBATCH * NPTS * 4);
    float*    cntf    = (float*)alloc((size_t)NBATCH * NPTS * 4);
    unsigned* pairs   = (unsigned*)alloc((size_t)NBATCH * 27 * CAP * 4);
    int*      paircnt = (int*)alloc((size_t)NBATCH * 27 * PCS * 4);
    unsigned* bitmap  = (unsigned*)alloc((size_t)NBATCH * BMW * 4);
    float*    bnsums  = (float*)alloc(256 * 4);
    float*    bnscale = (float*)alloc(128 * 4);
    float*    bnshift = (float*)alloc(128 * 4);
    float*    A       = (float*)alloc((size_t)NBATCH * NPTS * 64 * 4);  // vfeat(16) then h2(64)
    float*    Bb      = (float*)alloc((size_t)NBATCH * NPTS * 128 * 4); // h1(32) then h3(128)

    // ---- zero / sentinel inits (ws is poisoned each call) ----
    hipMemsetAsync(hashk, 0xFF, (size_t)NBATCH * TSIZE * 4, stream); // keys = -1
    hipMemsetAsync(scnt, 0, (size_t)NBATCH * TSIZE * 4, stream);
    hipMemsetAsync(nvox, 0, NBATCH * 4, stream);
    hipMemsetAsync(cntf, 0, (size_t)NBATCH * NPTS * 4, stream);
    hipMemsetAsync(A, 0, (size_t)NBATCH * NPTS * 16 * 4, stream);    // fsum region
    hipMemsetAsync(paircnt, 0, (size_t)NBATCH * 27 * PCS * 4, stream);
    hipMemsetAsync(bitmap, 0, (size_t)NBATCH * BMW * 4, stream);
    init_origin<<<1, 64, 0, stream>>>(origin);

    // ---- voxelization ----
    minred<<<512, 256, 0, stream>>>(xyz, origin);
    build_codes<<<dim3(NPTS / 256, NBATCH), 256, 0, stream>>>(xyz, origin, pslot, hashk, scnt);
    assign_ids<<<dim3(TSIZE / 256, NBATCH), 256, 0, stream>>>(hashk, hashv, nvox, voxcode,
                                                              bitmap, scnt, vnpts);
    point_pass<<<dim3(NPTS / 256, NBATCH), 256, 0, stream>>>(pslot, scnt, hashv, feat, mask,
                                                             inv, cntf, A);
    vfeat_div<<<dim3(NPTS / 256, NBATCH), 256, 0, stream>>>(A, cntf, vnpts, nvox);

    // ---- rulebook (shared by all 3 layers): thread per voxel, bitmap-probed ----
    build_pairs<<<dim3(NPTS / 256, NBATCH), 256, 0, stream>>>(hashk, hashv, voxcode,
                                                              nvox, bitmap, pairs, paircnt);

    dim3 cgrid1(NPTS / 64, NBATCH, 1);
    dim3 cgrid2(NPTS / 64, NBATCH, 1);
    dim3 cgrid3(NPTS / 64, NBATCH, 2);
    dim3 ogrid1(CAP / (PPB * CPB), NBATCH * 27, 1);
    dim3 ogrid2(CAP / (PPB * CPB), NBATCH * 27, 1);
    dim3 ogrid3(CAP / (PPB * CPB), NBATCH * 27, 2);

    // ---- layer 1: 16 -> 32 (no input transform) ----
    conv_center<16, 32, 32, false><<<cgrid1, 256, 0, stream>>>(A, Bb, W1 + 13 * 16 * 32, b1,
                                                               nullptr, nullptr, nvox);
    conv_off<16, 32, 32, false><<<ogrid1, 256, 0, stream>>>(A, Bb, W1, nullptr, nullptr,
                                                            pairs, paircnt);
    hipMemsetAsync(bnsums, 0, 256 * 4, stream);
    bn_stats<32><<<dim3(64, NBATCH), 256, 0, stream>>>(Bb, nvox, bnsums);
    bn_finalize<32><<<1, 128, 0, stream>>>(bnsums, nvox, g1, be1, bnscale, bnshift);

    // ---- layer 2: 32 -> 64 (fused BN1+ReLU on gather) ----
    conv_center<32, 64, 64, true><<<cgrid2, 256, 0, stream>>>(Bb, A, W2 + 13 * 32 * 64, b2,
                                                              bnscale, bnshift, nvox);
    conv_off<32, 64, 64, true><<<ogrid2, 256, 0, stream>>>(Bb, A, W2, bnscale, bnshift,
                                                           pairs, paircnt);
    hipMemsetAsync(bnsums, 0, 256 * 4, stream);
    bn_stats<64><<<dim3(64, NBATCH), 256, 0, stream>>>(A, nvox, bnsums);
    bn_finalize<64><<<1, 128, 0, stream>>>(bnsums, nvox, g2, be2, bnscale, bnshift);

    // ---- layer 3: 64 -> 128 (fused BN2+ReLU on gather, Cout split in 2) ----
    conv_center<64, 128, 64, true><<<cgrid3, 256, 0, stream>>>(A, Bb, W3 + 13 * 64 * 128, b3,
                                                               bnscale, bnshift, nvox);
    conv_off<64, 128, 64, true><<<ogrid3, 256, 0, stream>>>(A, Bb, W3, bnscale, bnshift,
                                                            pairs, paircnt);
    hipMemsetAsync(bnsums, 0, 256 * 4, stream);
    bn_stats<128><<<dim3(64, NBATCH), 256, 0, stream>>>(Bb, nvox, bnsums);
    bn_finalize<128><<<1, 128, 0, stream>>>(bnsums, nvox, g3, be3, bnscale, bnshift);

    // ---- fused BN3 + ReLU + gather + mask ----
    out_gather<<<dim3(NPTS * 128 / 256, NBATCH), 256, 0, stream>>>(Bb, inv, mask, bnscale,
                                                                   bnshift, out);
}

// Round 4
// 1762.706 us; speedup vs baseline: 1.2787x; 1.2787x over previous
//
#include <hip/hip_runtime.h>

#define NPTS   65536
#define NBATCH 8
#define TSIZE  131072
#define TM1    (TSIZE - 1)
#define CAP    8192     // pairs per (b,ko) bucket
#define PPB    64       // pairs per conv_off block
#define BMW    65536    // bitmap words per batch (2^21 bits)
#define STG    64       // LDS staging slots per bucket in build_pairs
#define PCS    16       // paircnt stride in ints (one 64B line per counter)

__device__ __forceinline__ unsigned hashf(int code) {
    unsigned u = (unsigned)code * 2654435761u;
    return (u >> 13) & TM1;
}

// ---------- init origin bits to +inf ----------
__global__ void init_origin(int* ob) {
    if (threadIdx.x < 3) ob[threadIdx.x] = 0x7F800000; // +inf
}

// ---------- global per-component min of xyz ----------
__global__ void minred(const float* __restrict__ xyz, int* __restrict__ ob) {
    int tid = threadIdx.x;
    float mx = INFINITY, my = INFINITY, mz = INFINITY;
    size_t total = (size_t)NBATCH * NPTS;
    for (size_t i = (size_t)blockIdx.x * blockDim.x + tid; i < total;
         i += (size_t)gridDim.x * blockDim.x) {
        mx = fminf(mx, xyz[i * 3 + 0]);
        my = fminf(my, xyz[i * 3 + 1]);
        mz = fminf(mz, xyz[i * 3 + 2]);
    }
    __shared__ float sx[256], sy[256], sz[256];
    sx[tid] = mx; sy[tid] = my; sz[tid] = mz;
    __syncthreads();
    for (int s = 128; s > 0; s >>= 1) {
        if (tid < s) {
            sx[tid] = fminf(sx[tid], sx[tid + s]);
            sy[tid] = fminf(sy[tid], sy[tid + s]);
            sz[tid] = fminf(sz[tid], sz[tid + s]);
        }
        __syncthreads();
    }
    if (tid == 0) {
        // coords >= 0 so signed-int compare of float bits preserves order
        atomicMin(&ob[0], __float_as_int(sx[0]));
        atomicMin(&ob[1], __float_as_int(sy[0]));
        atomicMin(&ob[2], __float_as_int(sz[0]));
    }
}

// ---------- voxel codes per point + hash insert + per-slot point count ----------
__global__ void build_codes(const float* __restrict__ xyz, const int* __restrict__ ob,
                            int* __restrict__ pslot, int* __restrict__ hashk,
                            int* __restrict__ scnt) {
    int b = blockIdx.y;
    int p = blockIdx.x * blockDim.x + threadIdx.x;
    size_t gi = (size_t)b * NPTS + p;
    float ox = __int_as_float(ob[0]);
    float oy = __int_as_float(ob[1]);
    float oz = __int_as_float(ob[2]);
    float x = xyz[gi * 3 + 0], y = xyz[gi * 3 + 1], z = xyz[gi * 3 + 2];
    int vx = (int)((x - ox) / 0.4f); if (vx < 0) vx = 0;
    int vy = (int)((y - oy) / 0.4f); if (vy < 0) vy = 0;
    int vz = (int)((z - oz) / 0.4f); if (vz < 0) vz = 0;
    int code = vx | (vy << 7) | (vz << 14);
    int* hk = hashk + (size_t)b * TSIZE;
    unsigned s = hashf(code);
    while (true) {
        int prev = atomicCAS(&hk[s], -1, code);
        if (prev == -1 || prev == code) break;
        s = (s + 1) & TM1;
    }
    pslot[gi] = (int)s;
    atomicAdd(&scnt[(size_t)b * TSIZE + s], 1);
}

// ---------- assign voxel ids to occupied hash slots + bitmap + per-voxel npts ----------
__global__ void assign_ids(const int* __restrict__ hashk, int* __restrict__ hashv,
                           int* __restrict__ nvox, int* __restrict__ voxcode,
                           unsigned* __restrict__ bitmap, const int* __restrict__ scnt,
                           int* __restrict__ vnpts) {
    int b = blockIdx.y;
    int s = blockIdx.x * blockDim.x + threadIdx.x;
    int k = hashk[(size_t)b * TSIZE + s];
    if (k != -1) {
        int id = atomicAdd(&nvox[b], 1);
        hashv[(size_t)b * TSIZE + s] = id;
        voxcode[(size_t)b * NPTS + id] = k;
        vnpts[(size_t)b * NPTS + id] = scnt[(size_t)b * TSIZE + s];
        atomicOr(&bitmap[(size_t)b * BMW + (k >> 5)], 1u << (k & 31));
    }
}

// ---------- per-point: record inv; single-point voxels store vfeat directly ----------
__global__ void point_pass(const int* __restrict__ pslot, const int* __restrict__ scnt,
                           const int* __restrict__ hashv, const float* __restrict__ feat,
                           const float* __restrict__ mask, int* __restrict__ inv,
                           float* __restrict__ cntf, float* __restrict__ fsum) {
    int b = blockIdx.y;
    int p = blockIdx.x * blockDim.x + threadIdx.x;
    size_t gi = (size_t)b * NPTS + p;
    int s = pslot[gi];
    int v = hashv[(size_t)b * TSIZE + s];
    inv[gi] = v;
    int n = scnt[(size_t)b * TSIZE + s];
    float m = mask[gi];
    const float4* f4 = (const float4*)(feat + gi * 16);
    float4 f0 = f4[0], f1 = f4[1], f2 = f4[2], f3 = f4[3];
    float* fs = fsum + ((size_t)b * NPTS + v) * 16;
    if (n == 1) {
        float4 o0 = {f0.x * m, f0.y * m, f0.z * m, f0.w * m};
        float4 o1 = {f1.x * m, f1.y * m, f1.z * m, f1.w * m};
        float4 o2 = {f2.x * m, f2.y * m, f2.z * m, f2.w * m};
        float4 o3 = {f3.x * m, f3.y * m, f3.z * m, f3.w * m};
        float4* fs4 = (float4*)fs;
        fs4[0] = o0; fs4[1] = o1; fs4[2] = o2; fs4[3] = o3;
    } else {
        atomicAdd(&cntf[(size_t)b * NPTS + v], m);
        atomicAdd(&fs[0],  f0.x * m); atomicAdd(&fs[1],  f0.y * m);
        atomicAdd(&fs[2],  f0.z * m); atomicAdd(&fs[3],  f0.w * m);
        atomicAdd(&fs[4],  f1.x * m); atomicAdd(&fs[5],  f1.y * m);
        atomicAdd(&fs[6],  f1.z * m); atomicAdd(&fs[7],  f1.w * m);
        atomicAdd(&fs[8],  f2.x * m); atomicAdd(&fs[9],  f2.y * m);
        atomicAdd(&fs[10], f2.z * m); atomicAdd(&fs[11], f2.w * m);
        atomicAdd(&fs[12], f3.x * m); atomicAdd(&fs[13], f3.y * m);
        atomicAdd(&fs[14], f3.z * m); atomicAdd(&fs[15], f3.w * m);
    }
}

// ---------- finish multi-point voxels: vfeat = fsum / max(cnt,1) ----------
__global__ void vfeat_div(float* __restrict__ fsum, const float* __restrict__ cntf,
                          const int* __restrict__ vnpts, const int* __restrict__ nvox) {
    int b = blockIdx.y;
    int v = blockIdx.x * blockDim.x + threadIdx.x;
    if (v >= nvox[b]) return;
    if (vnpts[(size_t)b * NPTS + v] <= 1) return;
    float cn = fmaxf(cntf[(size_t)b * NPTS + v], 1.0f);
    float* fs = fsum + ((size_t)b * NPTS + v) * 16;
    #pragma unroll
    for (int c = 0; c < 16; c++) fs[c] /= cn;
}

// ---------- build off-center rulebook (bitmap-probed, LDS-aggregated) ----------
__global__ __launch_bounds__(256) void build_pairs(
    const int* __restrict__ hashk, const int* __restrict__ hashv,
    const int* __restrict__ voxcode, const int* __restrict__ nvox,
    const unsigned* __restrict__ bitmap,
    unsigned* __restrict__ pairs, int* __restrict__ paircnt) {
    int b = blockIdx.y;
    int t = threadIdx.x;
    int v = blockIdx.x * 256 + t;
    __shared__ int lcnt[32];
    __shared__ int lbase[32];
    __shared__ unsigned s_pay[27 * STG];
    if (t < 32) lcnt[t] = 0;
    __syncthreads();

    bool active = (v < nvox[b]);
    int code = 0;
    if (active) code = voxcode[(size_t)b * NPTS + v];
    int x = code & 127, y = (code >> 7) & 127, z = code >> 14;
    const unsigned* bm = bitmap + (size_t)b * BMW;
    const int* hk = hashk + (size_t)b * TSIZE;
    const int* hv = hashv + (size_t)b * TSIZE;

    // phase A: 13 independent bitmap loads -> hitmask
    int ncode[13];
    unsigned hitmask = 0;
    #pragma unroll
    for (int d = 0; d < 13; d++) {
        int dz = d / 9 - 1, r9 = d % 9;
        int dy = r9 / 3 - 1, dx = r9 % 3 - 1;
        int nx = x + dx, ny = y + dy, nz = z + dz;
        bool inb = active && ((unsigned)nx <= 127u) && ((unsigned)ny <= 127u) &&
                   ((unsigned)nz <= 127u);
        int nc = nx | (ny << 7) | (nz << 14);
        ncode[d] = nc;
        unsigned w = 0;
        if (inb) w = bm[nc >> 5];
        if (inb && ((w >> (nc & 31)) & 1u)) hitmask |= 1u << d;
    }

    // phase B: resolve ids for hits, stage pair emissions in LDS
    #pragma unroll
    for (int d = 0; d < 13; d++) {
        if (hitmask & (1u << d)) {
            int nc = ncode[d];
            unsigned s = hashf(nc);
            int nb = -1;
            while (true) {
                int k = hk[s];
                if (k == nc) { nb = hv[s]; break; }
                if (k == -1) break;  // safety; bitmap==hash by construction
                s = (s + 1) & TM1;
            }
            if (nb >= 0) {
                unsigned p1 = ((unsigned)v << 16) | (unsigned)nb;
                unsigned p2 = ((unsigned)nb << 16) | (unsigned)v;
                int l1 = atomicAdd(&lcnt[d], 1);
                if (l1 < STG) {
                    s_pay[d * STG + l1] = p1;
                } else {  // rare overflow: direct global slot (disjoint from bulk)
                    int gs = atomicAdd(&paircnt[(b * 27 + d) * PCS], 1);
                    if (gs < CAP) pairs[(size_t)(b * 27 + d) * CAP + gs] = p1;
                }
                int k2 = 26 - d;
                int l2 = atomicAdd(&lcnt[k2], 1);
                if (l2 < STG) {
                    s_pay[k2 * STG + l2] = p2;
                } else {
                    int gs = atomicAdd(&paircnt[(b * 27 + k2) * PCS], 1);
                    if (gs < CAP) pairs[(size_t)(b * 27 + k2) * CAP + gs] = p2;
                }
            }
        }
    }
    __syncthreads();

    if (t < 27) {
        int n = lcnt[t]; if (n > STG) n = STG;
        lbase[t] = (n > 0) ? atomicAdd(&paircnt[(b * 27 + t) * PCS], n) : 0;
    }
    __syncthreads();

    for (int k = t; k < 27 * STG; k += 256) {
        int bkt = k / STG, i = k % STG;
        int n = lcnt[bkt]; if (n > STG) n = STG;
        if (i < n) {
            int gs = lbase[bkt] + i;
            if (gs < CAP) pairs[(size_t)(b * 27 + bkt) * CAP + gs] = s_pay[k];
        }
    }
}

// ---------- dense center GEMM with in-block sequential Cout halves ----------
// NSPL: number of sequential Cout slices sharing one A_s staging. W_s holds one
// slice (Cout/NSPL cols); between slices the block re-stages W_s (two barriers,
// nothing else outstanding -> cheap). All output stores happen at the END so no
// barrier ever drains pending stores. A_s bank swizzle: (ci,r) stored at
// [ci][r ^ (ci & 28)] -> transpose-store conflicts drop to <=2-way (free); MAC
// reads are broadcast / conflict-free; float4 alignment preserved.
template <int Cin, int Cout, int NSPL, bool XFORM>
__global__ __launch_bounds__(256) void conv_center(
    const float* __restrict__ in, float* __restrict__ outp,
    const float* __restrict__ W13, const float* __restrict__ bias,
    const float* __restrict__ sc, const float* __restrict__ sh,
    const int* __restrict__ nvox) {
    constexpr int BR   = 64;
    constexpr int COLS = Cout / NSPL;
    constexpr int CT   = COLS;
    constexpr int RG   = 256 / CT;
    constexpr int RPT  = BR / RG;
    int b = blockIdx.y;
    int nv = nvox[b];
    int v0 = blockIdx.x * BR;
    if (v0 >= nv) return;
    __shared__ __align__(16) float A_s[Cin][BR + 4];
    __shared__ __align__(16) float W_s[Cin * COLS];
    int t = threadIdx.x;
    for (int i4 = t; i4 < Cin * COLS / 4; i4 += 256) {
        int lin = i4 * 4;
        int ci = lin / COLS, cc = lin % COLS;
        *(float4*)&W_s[lin] = *(const float4*)&W13[(size_t)ci * Cout + cc];
    }
    const float* inb = in + (size_t)b * NPTS * Cin;
    for (int i4 = t; i4 < BR * Cin / 4; i4 += 256) {
        int lin = i4 * 4;
        int r = lin / Cin, ci = lin % Cin;
        float4 val = *(const float4*)&inb[(size_t)(v0 + r) * Cin + ci];
        if (XFORM) {
            val.x = fmaxf(val.x * sc[ci + 0] + sh[ci + 0], 0.0f);
            val.y = fmaxf(val.y * sc[ci + 1] + sh[ci + 1], 0.0f);
            val.z = fmaxf(val.z * sc[ci + 2] + sh[ci + 2], 0.0f);
            val.w = fmaxf(val.w * sc[ci + 3] + sh[ci + 3], 0.0f);
        }
        A_s[ci + 0][r ^ ((ci + 0) & 28)] = val.x;
        A_s[ci + 1][r ^ ((ci + 1) & 28)] = val.y;
        A_s[ci + 2][r ^ ((ci + 2) & 28)] = val.z;
        A_s[ci + 3][r ^ ((ci + 3) & 28)] = val.w;
    }
    __syncthreads();
    int c = t % CT;
    int r0 = (t / CT) * RPT;
    float acc[NSPL][RPT];
    #pragma unroll
    for (int h = 0; h < NSPL; h++) {
        if (h > 0) {
            __syncthreads();   // all waves done reading previous W_s slice
            for (int i4 = t; i4 < Cin * COLS / 4; i4 += 256) {
                int lin = i4 * 4;
                int ci = lin / COLS, cc = lin % COLS;
                *(float4*)&W_s[lin] = *(const float4*)&W13[(size_t)ci * Cout + h * COLS + cc];
            }
            __syncthreads();
        }
        #pragma unroll
        for (int r = 0; r < RPT; r++) acc[h][r] = 0.0f;
        #pragma unroll 4
        for (int ci = 0; ci < Cin; ci++) {
            int sw = ci & 28;
            float w = W_s[ci * COLS + c];
            #pragma unroll
            for (int k = 0; k < RPT / 4; k++) {
                float4 a4 = *(const float4*)&A_s[ci][(r0 + 4 * k) ^ sw];
                acc[h][4 * k + 0] += a4.x * w;
                acc[h][4 * k + 1] += a4.y * w;
                acc[h][4 * k + 2] += a4.z * w;
                acc[h][4 * k + 3] += a4.w * w;
            }
        }
    }
    float* ob = outp + (size_t)b * NPTS * Cout;
    #pragma unroll
    for (int h = 0; h < NSPL; h++) {
        float bs = bias[h * COLS + c];
        #pragma unroll
        for (int r = 0; r < RPT; r++) {
            int row = v0 + r0 + r;
            if (row < nv)
                ob[(size_t)row * Cout + h * COLS + c] = acc[h][r] + bs;
        }
    }
}

// ---------- off-center: gather 64 pair-rows, GEMM, scatter-add at END ----------
// Round-2 structure (one chunk per block, atomics drain at kernel end overlapped
// across blocks) + NSPL sequential Cout slices sharing one A_s gather (halves W_s
// LDS for the 64->128 layer: 50.7KB -> 34KB -> 4 blocks/CU) + bank swizzle.
template <int Cin, int Cout, int NSPL, bool XFORM>
__global__ __launch_bounds__(256) void conv_off(
    const float* __restrict__ in, float* __restrict__ outp,
    const float* __restrict__ W, const float* __restrict__ sc,
    const float* __restrict__ sh, const unsigned* __restrict__ pairs,
    const int* __restrict__ paircnt) {
    constexpr int BR   = PPB;
    constexpr int COLS = Cout / NSPL;
    constexpr int CT   = COLS;
    constexpr int RG   = 256 / CT;
    constexpr int RPT  = BR / RG;
    int bk = blockIdx.y;            // b*27 + ko
    int ko = bk % 27;
    int b  = bk / 27;
    int cnt = paircnt[bk * PCS];
    if (cnt > CAP) cnt = CAP;
    int start = blockIdx.x * BR;
    if (start >= cnt) return;
    int nActive = cnt - start; if (nActive > BR) nActive = BR;
    __shared__ __align__(16) float A_s[Cin][BR + 4];
    __shared__ __align__(16) float W_s[Cin * COLS];
    __shared__ unsigned pr_s[BR];
    int t = threadIdx.x;
    const float* Wk = W + (size_t)ko * Cin * Cout;
    for (int i4 = t; i4 < Cin * COLS / 4; i4 += 256) {
        int lin = i4 * 4;
        int ci = lin / COLS, cc = lin % COLS;
        *(float4*)&W_s[lin] = *(const float4*)&Wk[(size_t)ci * Cout + cc];
    }
    const unsigned* pb = pairs + (size_t)bk * CAP + start;
    if (t < BR) pr_s[t] = pb[t];
    __syncthreads();
    const float* inb = in + (size_t)b * NPTS * Cin;
    for (int i4 = t; i4 < BR * Cin / 4; i4 += 256) {
        int lin = i4 * 4;
        int r = lin / Cin, ci = lin % Cin;
        int vin = (int)(pr_s[r] & 0xffffu);
        float4 val = *(const float4*)&inb[(size_t)vin * Cin + ci];
        if (XFORM) {
            val.x = fmaxf(val.x * sc[ci + 0] + sh[ci + 0], 0.0f);
            val.y = fmaxf(val.y * sc[ci + 1] + sh[ci + 1], 0.0f);
            val.z = fmaxf(val.z * sc[ci + 2] + sh[ci + 2], 0.0f);
            val.w = fmaxf(val.w * sc[ci + 3] + sh[ci + 3], 0.0f);
        }
        A_s[ci + 0][r ^ ((ci + 0) & 28)] = val.x;
        A_s[ci + 1][r ^ ((ci + 1) & 28)] = val.y;
        A_s[ci + 2][r ^ ((ci + 2) & 28)] = val.z;
        A_s[ci + 3][r ^ ((ci + 3) & 28)] = val.w;
    }
    __syncthreads();
    int c = t % CT;
    int r0 = (t / CT) * RPT;
    float acc[NSPL][RPT];
    #pragma unroll
    for (int h = 0; h < NSPL; h++) {
        if (h > 0) {
            __syncthreads();   // nothing outstanding: atomics haven't been issued yet
            for (int i4 = t; i4 < Cin * COLS / 4; i4 += 256) {
                int lin = i4 * 4;
                int ci = lin / COLS, cc = lin % COLS;
                *(float4*)&W_s[lin] = *(const float4*)&Wk[(size_t)ci * Cout + h * COLS + cc];
            }
            __syncthreads();
        }
        #pragma unroll
        for (int r = 0; r < RPT; r++) acc[h][r] = 0.0f;
        #pragma unroll 4
        for (int ci = 0; ci < Cin; ci++) {
            int sw = ci & 28;
            float w = W_s[ci * COLS + c];
            #pragma unroll
            for (int k = 0; k < RPT / 4; k++) {
                float4 a4 = *(const float4*)&A_s[ci][(r0 + 4 * k) ^ sw];
                acc[h][4 * k + 0] += a4.x * w;
                acc[h][4 * k + 1] += a4.y * w;
                acc[h][4 * k + 2] += a4.z * w;
                acc[h][4 * k + 3] += a4.w * w;
            }
        }
    }
    float* ob = outp + (size_t)b * NPTS * Cout;
    #pragma unroll
    for (int h = 0; h < NSPL; h++) {
        #pragma unroll
        for (int r = 0; r < RPT; r++) {
            if (r0 + r < nActive) {
                int vout = (int)(pr_s[r0 + r] >> 16);
                atomicAdd(&ob[(size_t)vout * Cout + h * COLS + c], acc[h][r]);
            }
        }
    }
}

// ---------- BN stats: per-channel sum and sumsq over valid voxels ----------
template <int C>
__global__ void bn_stats(const float* __restrict__ h, const int* __restrict__ nvox,
                         float* __restrict__ sums) {
    constexpr int RPB = 256 / C;
    int b = blockIdx.y;
    int nv = nvox[b];
    int tid = threadIdx.x;
    int c = tid % C;
    int r = tid / C;
    float s0 = 0.0f, s1 = 0.0f;
    for (int v = blockIdx.x * RPB + r; v < nv; v += gridDim.x * RPB) {
        float x = h[((size_t)b * NPTS + v) * C + c];
        s0 += x;
        s1 += x * x;
    }
    __shared__ float l0[256], l1[256];
    l0[tid] = s0; l1[tid] = s1;
    __syncthreads();
    for (int s = 128; s >= C; s >>= 1) {
        if (tid < s) { l0[tid] += l0[tid + s]; l1[tid] += l1[tid + s]; }
        __syncthreads();
    }
    if (tid < C) {
        atomicAdd(&sums[c], l0[tid]);
        atomicAdd(&sums[C + c], l1[tid]);
    }
}

template <int C>
__global__ void bn_finalize(const float* __restrict__ sums, const int* __restrict__ nvox,
                            const float* __restrict__ g, const float* __restrict__ be,
                            float* __restrict__ scale, float* __restrict__ shift) {
    int c = threadIdx.x;
    if (c >= C) return;
    float n = 0.0f;
    for (int b = 0; b < NBATCH; b++) n += (float)nvox[b];
    n = fmaxf(n, 1.0f);
    float mean = sums[c] / n;
    float var = sums[C + c] / n - mean * mean;
    float a = g[c] * rsqrtf(var + 1e-5f);
    scale[c] = a;
    shift[c] = be[c] - mean * a;
}

// ---------- fused BN3 + ReLU + gather to points + mask ----------
__global__ void out_gather(const float* __restrict__ h3, const int* __restrict__ inv,
                           const float* __restrict__ mask, const float* __restrict__ sc,
                           const float* __restrict__ sh, float* __restrict__ out) {
    int b = blockIdx.y;
    size_t i = (size_t)blockIdx.x * blockDim.x + threadIdx.x; // over NPTS*128
    int p = (int)(i >> 7);
    int c = (int)(i & 127);
    size_t gi = (size_t)b * NPTS + p;
    int v = inv[gi];
    float m = mask[gi];
    float x = h3[((size_t)b * NPTS + v) * 128 + c];
    x = fmaxf(x * sc[c] + sh[c], 0.0f);
    out[gi * 128 + c] = x * m;
}

extern "C" void kernel_launch(void* const* d_in, const int* in_sizes, int n_in,
                              void* d_out, int out_size, void* d_ws, size_t ws_size,
                              hipStream_t stream) {
    const float* xyz  = (const float*)d_in[0];
    const float* feat = (const float*)d_in[1];
    const float* mask = (const float*)d_in[2];
    const float* W1 = (const float*)d_in[3];
    const float* b1 = (const float*)d_in[4];
    const float* g1 = (const float*)d_in[5];
    const float* be1 = (const float*)d_in[6];
    const float* W2 = (const float*)d_in[7];
    const float* b2 = (const float*)d_in[8];
    const float* g2 = (const float*)d_in[9];
    const float* be2 = (const float*)d_in[10];
    const float* W3 = (const float*)d_in[11];
    const float* b3 = (const float*)d_in[12];
    const float* g3 = (const float*)d_in[13];
    const float* be3 = (const float*)d_in[14];
    float* out = (float*)d_out;

    char* ws = (char*)d_ws;
    size_t off = 0;
    auto alloc = [&](size_t bytes) {
        void* p = ws + off;
        off += (bytes + 255) & ~(size_t)255;
        return p;
    };
    int*      hashk   = (int*)alloc((size_t)NBATCH * TSIZE * 4);
    int*      hashv   = (int*)alloc((size_t)NBATCH * TSIZE * 4);
    int*      scnt    = (int*)alloc((size_t)NBATCH * TSIZE * 4);
    int*      nvox    = (int*)alloc(NBATCH * 4);
    int*      origin  = (int*)alloc(16);
    int*      pslot   = (int*)alloc((size_t)NBATCH * NPTS * 4);
    int*      voxcode = (int*)alloc((size_t)NBATCH * NPTS * 4);
    int*      vnpts   = (int*)alloc((size_t)NBATCH * NPTS * 4);
    int*      inv     = (int*)alloc((size_t)NBATCH * NPTS * 4);
    float*    cntf    = (float*)alloc((size_t)NBATCH * NPTS * 4);
    unsigned* pairs   = (unsigned*)alloc((size_t)NBATCH * 27 * CAP * 4);
    int*      paircnt = (int*)alloc((size_t)NBATCH * 27 * PCS * 4);
    unsigned* bitmap  = (unsigned*)alloc((size_t)NBATCH * BMW * 4);
    float*    bnsums  = (float*)alloc(256 * 4);
    float*    bnscale = (float*)alloc(128 * 4);
    float*    bnshift = (float*)alloc(128 * 4);
    float*    A       = (float*)alloc((size_t)NBATCH * NPTS * 64 * 4);  // vfeat(16) then h2(64)
    float*    Bb      = (float*)alloc((size_t)NBATCH * NPTS * 128 * 4); // h1(32) then h3(128)

    // ---- zero / sentinel inits (ws is poisoned each call) ----
    hipMemsetAsync(hashk, 0xFF, (size_t)NBATCH * TSIZE * 4, stream); // keys = -1
    hipMemsetAsync(scnt, 0, (size_t)NBATCH * TSIZE * 4, stream);
    hipMemsetAsync(nvox, 0, NBATCH * 4, stream);
    hipMemsetAsync(cntf, 0, (size_t)NBATCH * NPTS * 4, stream);
    hipMemsetAsync(A, 0, (size_t)NBATCH * NPTS * 16 * 4, stream);    // fsum region
    hipMemsetAsync(paircnt, 0, (size_t)NBATCH * 27 * PCS * 4, stream);
    hipMemsetAsync(bitmap, 0, (size_t)NBATCH * BMW * 4, stream);
    init_origin<<<1, 64, 0, stream>>>(origin);

    // ---- voxelization ----
    minred<<<512, 256, 0, stream>>>(xyz, origin);
    build_codes<<<dim3(NPTS / 256, NBATCH), 256, 0, stream>>>(xyz, origin, pslot, hashk, scnt);
    assign_ids<<<dim3(TSIZE / 256, NBATCH), 256, 0, stream>>>(hashk, hashv, nvox, voxcode,
                                                              bitmap, scnt, vnpts);
    point_pass<<<dim3(NPTS / 256, NBATCH), 256, 0, stream>>>(pslot, scnt, hashv, feat, mask,
                                                             inv, cntf, A);
    vfeat_div<<<dim3(NPTS / 256, NBATCH), 256, 0, stream>>>(A, cntf, vnpts, nvox);

    // ---- rulebook (shared by all 3 layers): thread per voxel, bitmap-probed ----
    build_pairs<<<dim3(NPTS / 256, NBATCH), 256, 0, stream>>>(hashk, hashv, voxcode,
                                                              nvox, bitmap, pairs, paircnt);

    dim3 cgrid(NPTS / 64, NBATCH);
    dim3 ogrid(CAP / PPB, NBATCH * 27);

    // ---- layer 1: 16 -> 32 (no input transform) ----
    conv_center<16, 32, 1, false><<<cgrid, 256, 0, stream>>>(A, Bb, W1 + 13 * 16 * 32, b1,
                                                             nullptr, nullptr, nvox);
    conv_off<16, 32, 1, false><<<ogrid, 256, 0, stream>>>(A, Bb, W1, nullptr, nullptr,
                                                          pairs, paircnt);
    hipMemsetAsync(bnsums, 0, 256 * 4, stream);
    bn_stats<32><<<dim3(64, NBATCH), 256, 0, stream>>>(Bb, nvox, bnsums);
    bn_finalize<32><<<1, 128, 0, stream>>>(bnsums, nvox, g1, be1, bnscale, bnshift);

    // ---- layer 2: 32 -> 64 (fused BN1+ReLU on gather) ----
    conv_center<32, 64, 1, true><<<cgrid, 256, 0, stream>>>(Bb, A, W2 + 13 * 32 * 64, b2,
                                                            bnscale, bnshift, nvox);
    conv_off<32, 64, 1, true><<<ogrid, 256, 0, stream>>>(Bb, A, W2, bnscale, bnshift,
                                                         pairs, paircnt);
    hipMemsetAsync(bnsums, 0, 256 * 4, stream);
    bn_stats<64><<<dim3(64, NBATCH), 256, 0, stream>>>(A, nvox, bnsums);
    bn_finalize<64><<<1, 128, 0, stream>>>(bnsums, nvox, g2, be2, bnscale, bnshift);

    // ---- layer 3: 64 -> 128 (fused BN2+ReLU on gather; 2 sequential Cout halves) ----
    conv_center<64, 128, 2, true><<<cgrid, 256, 0, stream>>>(A, Bb, W3 + 13 * 64 * 128, b3,
                                                             bnscale, bnshift, nvox);
    conv_off<64, 128, 2, true><<<ogrid, 256, 0, stream>>>(A, Bb, W3, bnscale, bnshift,
                                                          pairs, paircnt);
    hipMemsetAsync(bnsums, 0, 256 * 4, stream);
    bn_stats<128><<<dim3(64, NBATCH), 256, 0, stream>>>(Bb, nvox, bnsums);
    bn_finalize<128><<<1, 128, 0, stream>>>(bnsums, nvox, g3, be3, bnscale, bnshift);

    // ---- fused BN3 + ReLU + gather + mask ----
    out_gather<<<dim3(NPTS * 128 / 256, NBATCH), 256, 0, stream>>>(Bb, inv, mask, bnscale,
                                                                   bnshift, out);
}

// Round 5
// 1445.804 us; speedup vs baseline: 1.5589x; 1.2192x over previous
//
#include <hip/hip_runtime.h>

#define NPTS   65536
#define NBATCH 8
#define TSIZE  131072
#define TM1    (TSIZE - 1)
#define CAP    8192     // pairs per (b,ko) bucket
#define PPB    64       // pairs per conv_off block
#define BMW    65536    // bitmap words per batch (2^21 bits)
#define STG    64       // LDS staging slots per bucket in build_pairs
#define PCS    16       // paircnt stride in ints (one 64B line per counter)

__device__ __forceinline__ unsigned hashf(int code) {
    unsigned u = (unsigned)code * 2654435761u;
    return (u >> 13) & TM1;
}

// ---------- init origin bits to +inf ----------
__global__ void init_origin(int* ob) {
    if (threadIdx.x < 3) ob[threadIdx.x] = 0x7F800000; // +inf
}

// ---------- global per-component min of xyz ----------
__global__ void minred(const float* __restrict__ xyz, int* __restrict__ ob) {
    int tid = threadIdx.x;
    float mx = INFINITY, my = INFINITY, mz = INFINITY;
    size_t total = (size_t)NBATCH * NPTS;
    for (size_t i = (size_t)blockIdx.x * blockDim.x + tid; i < total;
         i += (size_t)gridDim.x * blockDim.x) {
        mx = fminf(mx, xyz[i * 3 + 0]);
        my = fminf(my, xyz[i * 3 + 1]);
        mz = fminf(mz, xyz[i * 3 + 2]);
    }
    __shared__ float sx[256], sy[256], sz[256];
    sx[tid] = mx; sy[tid] = my; sz[tid] = mz;
    __syncthreads();
    for (int s = 128; s > 0; s >>= 1) {
        if (tid < s) {
            sx[tid] = fminf(sx[tid], sx[tid + s]);
            sy[tid] = fminf(sy[tid], sy[tid + s]);
            sz[tid] = fminf(sz[tid], sz[tid + s]);
        }
        __syncthreads();
    }
    if (tid == 0) {
        // coords >= 0 so signed-int compare of float bits preserves order
        atomicMin(&ob[0], __float_as_int(sx[0]));
        atomicMin(&ob[1], __float_as_int(sy[0]));
        atomicMin(&ob[2], __float_as_int(sz[0]));
    }
}

// ---------- voxel codes per point + hash insert + per-slot point count ----------
__global__ void build_codes(const float* __restrict__ xyz, const int* __restrict__ ob,
                            int* __restrict__ pslot, int* __restrict__ hashk,
                            int* __restrict__ scnt) {
    int b = blockIdx.y;
    int p = blockIdx.x * blockDim.x + threadIdx.x;
    size_t gi = (size_t)b * NPTS + p;
    float ox = __int_as_float(ob[0]);
    float oy = __int_as_float(ob[1]);
    float oz = __int_as_float(ob[2]);
    float x = xyz[gi * 3 + 0], y = xyz[gi * 3 + 1], z = xyz[gi * 3 + 2];
    int vx = (int)((x - ox) / 0.4f); if (vx < 0) vx = 0;
    int vy = (int)((y - oy) / 0.4f); if (vy < 0) vy = 0;
    int vz = (int)((z - oz) / 0.4f); if (vz < 0) vz = 0;
    int code = vx | (vy << 7) | (vz << 14);
    int* hk = hashk + (size_t)b * TSIZE;
    unsigned s = hashf(code);
    while (true) {
        int prev = atomicCAS(&hk[s], -1, code);
        if (prev == -1 || prev == code) break;
        s = (s + 1) & TM1;
    }
    pslot[gi] = (int)s;
    atomicAdd(&scnt[(size_t)b * TSIZE + s], 1);
}

// ---------- assign voxel ids: ballot-aggregated (1 global atomic per block) ----------
__global__ void assign_ids(const int* __restrict__ hashk, int* __restrict__ hashv,
                           int* __restrict__ nvox, int* __restrict__ voxcode,
                           unsigned* __restrict__ bitmap, const int* __restrict__ scnt,
                           int* __restrict__ vnpts) {
    int b = blockIdx.y;
    int s = blockIdx.x * blockDim.x + threadIdx.x;
    int k = hashk[(size_t)b * TSIZE + s];
    unsigned long long vote = __ballot(k != -1);
    __shared__ int wbase[4];
    int wid = threadIdx.x >> 6, lane = threadIdx.x & 63;
    if (lane == 0) wbase[wid] = __popcll(vote);
    __syncthreads();
    if (threadIdx.x == 0) {
        int c0 = wbase[0], c1 = wbase[1], c2 = wbase[2], c3 = wbase[3];
        int base = atomicAdd(&nvox[b], c0 + c1 + c2 + c3);
        wbase[0] = base;
        wbase[1] = base + c0;
        wbase[2] = base + c0 + c1;
        wbase[3] = base + c0 + c1 + c2;
    }
    __syncthreads();
    if (k != -1) {
        int id = wbase[wid] + __popcll(vote & ((1ull << lane) - 1ull));
        hashv[(size_t)b * TSIZE + s] = id;
        voxcode[(size_t)b * NPTS + id] = k;
        vnpts[(size_t)b * NPTS + id] = scnt[(size_t)b * TSIZE + s];
        atomicOr(&bitmap[(size_t)b * BMW + (k >> 5)], 1u << (k & 31));
    }
}

// ---------- per-point: record inv; single-point voxels store vfeat directly ----------
__global__ void point_pass(const int* __restrict__ pslot, const int* __restrict__ scnt,
                           const int* __restrict__ hashv, const float* __restrict__ feat,
                           const float* __restrict__ mask, int* __restrict__ inv,
                           float* __restrict__ cntf, float* __restrict__ fsum) {
    int b = blockIdx.y;
    int p = blockIdx.x * blockDim.x + threadIdx.x;
    size_t gi = (size_t)b * NPTS + p;
    int s = pslot[gi];
    int v = hashv[(size_t)b * TSIZE + s];
    inv[gi] = v;
    int n = scnt[(size_t)b * TSIZE + s];
    float m = mask[gi];
    const float4* f4 = (const float4*)(feat + gi * 16);
    float4 f0 = f4[0], f1 = f4[1], f2 = f4[2], f3 = f4[3];
    float* fs = fsum + ((size_t)b * NPTS + v) * 16;
    if (n == 1) {
        float4 o0 = {f0.x * m, f0.y * m, f0.z * m, f0.w * m};
        float4 o1 = {f1.x * m, f1.y * m, f1.z * m, f1.w * m};
        float4 o2 = {f2.x * m, f2.y * m, f2.z * m, f2.w * m};
        float4 o3 = {f3.x * m, f3.y * m, f3.z * m, f3.w * m};
        float4* fs4 = (float4*)fs;
        fs4[0] = o0; fs4[1] = o1; fs4[2] = o2; fs4[3] = o3;
    } else {
        atomicAdd(&cntf[(size_t)b * NPTS + v], m);
        atomicAdd(&fs[0],  f0.x * m); atomicAdd(&fs[1],  f0.y * m);
        atomicAdd(&fs[2],  f0.z * m); atomicAdd(&fs[3],  f0.w * m);
        atomicAdd(&fs[4],  f1.x * m); atomicAdd(&fs[5],  f1.y * m);
        atomicAdd(&fs[6],  f1.z * m); atomicAdd(&fs[7],  f1.w * m);
        atomicAdd(&fs[8],  f2.x * m); atomicAdd(&fs[9],  f2.y * m);
        atomicAdd(&fs[10], f2.z * m); atomicAdd(&fs[11], f2.w * m);
        atomicAdd(&fs[12], f3.x * m); atomicAdd(&fs[13], f3.y * m);
        atomicAdd(&fs[14], f3.z * m); atomicAdd(&fs[15], f3.w * m);
    }
}

// ---------- finish multi-point voxels: vfeat = fsum / max(cnt,1) ----------
__global__ void vfeat_div(float* __restrict__ fsum, const float* __restrict__ cntf,
                          const int* __restrict__ vnpts, const int* __restrict__ nvox) {
    int b = blockIdx.y;
    int v = blockIdx.x * blockDim.x + threadIdx.x;
    if (v >= nvox[b]) return;
    if (vnpts[(size_t)b * NPTS + v] <= 1) return;
    float cn = fmaxf(cntf[(size_t)b * NPTS + v], 1.0f);
    float* fs = fsum + ((size_t)b * NPTS + v) * 16;
    #pragma unroll
    for (int c = 0; c < 16; c++) fs[c] /= cn;
}

// ---------- build off-center rulebook (bitmap-probed, LDS-aggregated) ----------
__global__ __launch_bounds__(256) void build_pairs(
    const int* __restrict__ hashk, const int* __restrict__ hashv,
    const int* __restrict__ voxcode, const int* __restrict__ nvox,
    const unsigned* __restrict__ bitmap,
    unsigned* __restrict__ pairs, int* __restrict__ paircnt) {
    int b = blockIdx.y;
    int t = threadIdx.x;
    int v = blockIdx.x * 256 + t;
    __shared__ int lcnt[32];
    __shared__ int lbase[32];
    __shared__ unsigned s_pay[27 * STG];
    if (t < 32) lcnt[t] = 0;
    __syncthreads();

    bool active = (v < nvox[b]);
    int code = 0;
    if (active) code = voxcode[(size_t)b * NPTS + v];
    int x = code & 127, y = (code >> 7) & 127, z = code >> 14;
    const unsigned* bm = bitmap + (size_t)b * BMW;
    const int* hk = hashk + (size_t)b * TSIZE;
    const int* hv = hashv + (size_t)b * TSIZE;

    // phase A: 13 independent bitmap loads -> hitmask
    int ncode[13];
    unsigned hitmask = 0;
    #pragma unroll
    for (int d = 0; d < 13; d++) {
        int dz = d / 9 - 1, r9 = d % 9;
        int dy = r9 / 3 - 1, dx = r9 % 3 - 1;
        int nx = x + dx, ny = y + dy, nz = z + dz;
        bool inb = active && ((unsigned)nx <= 127u) && ((unsigned)ny <= 127u) &&
                   ((unsigned)nz <= 127u);
        int nc = nx | (ny << 7) | (nz << 14);
        ncode[d] = nc;
        unsigned w = 0;
        if (inb) w = bm[nc >> 5];
        if (inb && ((w >> (nc & 31)) & 1u)) hitmask |= 1u << d;
    }

    // phase B: resolve ids for hits, stage pair emissions in LDS
    #pragma unroll
    for (int d = 0; d < 13; d++) {
        if (hitmask & (1u << d)) {
            int nc = ncode[d];
            unsigned s = hashf(nc);
            int nb = -1;
            while (true) {
                int k = hk[s];
                if (k == nc) { nb = hv[s]; break; }
                if (k == -1) break;  // safety; bitmap==hash by construction
                s = (s + 1) & TM1;
            }
            if (nb >= 0) {
                unsigned p1 = ((unsigned)v << 16) | (unsigned)nb;
                unsigned p2 = ((unsigned)nb << 16) | (unsigned)v;
                int l1 = atomicAdd(&lcnt[d], 1);
                if (l1 < STG) {
                    s_pay[d * STG + l1] = p1;
                } else {  // rare overflow: direct global slot (disjoint from bulk)
                    int gs = atomicAdd(&paircnt[(b * 27 + d) * PCS], 1);
                    if (gs < CAP) pairs[(size_t)(b * 27 + d) * CAP + gs] = p1;
                }
                int k2 = 26 - d;
                int l2 = atomicAdd(&lcnt[k2], 1);
                if (l2 < STG) {
                    s_pay[k2 * STG + l2] = p2;
                } else {
                    int gs = atomicAdd(&paircnt[(b * 27 + k2) * PCS], 1);
                    if (gs < CAP) pairs[(size_t)(b * 27 + k2) * CAP + gs] = p2;
                }
            }
        }
    }
    __syncthreads();

    if (t < 27) {
        int n = lcnt[t]; if (n > STG) n = STG;
        lbase[t] = (n > 0) ? atomicAdd(&paircnt[(b * 27 + t) * PCS], n) : 0;
    }
    __syncthreads();

    for (int k = t; k < 27 * STG; k += 256) {
        int bkt = k / STG, i = k % STG;
        int n = lcnt[bkt]; if (n > STG) n = STG;
        if (i < n) {
            int gs = lbase[bkt] + i;
            if (gs < CAP) pairs[(size_t)(b * 27 + bkt) * CAP + gs] = s_pay[k];
        }
    }
}

// ---------- dense center GEMM; W read from L2 (no W_s) ----------
// W stays in L2 (<=64KB/layer, shared by all blocks): per ci a wave issues one
// coalesced 256B load per col-group, reused across RPT rows of FMAs. Dropping
// W_s halves LDS (17.7KB) -> ~6-8 blocks/CU and removes the staging barrier.
// A_s bank swizzle: (ci,r) at [ci][r ^ (ci & 28)] -> store conflicts <=2-way.
template <int Cin, int Cout, bool XFORM>
__global__ __launch_bounds__(256, 4) void conv_center(
    const float* __restrict__ in, float* __restrict__ outp,
    const float* __restrict__ W13, const float* __restrict__ bias,
    const float* __restrict__ sc, const float* __restrict__ sh,
    const int* __restrict__ nvox) {
    constexpr int BR  = 64;
    constexpr int CT  = (Cout < 64) ? Cout : 64;
    constexpr int RG  = 256 / CT;
    constexpr int RPT = BR / RG;
    constexpr int J   = Cout / CT;
    int b = blockIdx.y;
    int nv = nvox[b];
    int v0 = blockIdx.x * BR;
    if (v0 >= nv) return;
    __shared__ __align__(16) float A_s[Cin][BR + 4];
    int t = threadIdx.x;
    const float* inb = in + (size_t)b * NPTS * Cin;
    for (int i4 = t; i4 < BR * Cin / 4; i4 += 256) {
        int lin = i4 * 4;
        int r = lin / Cin, ci = lin % Cin;
        float4 val = *(const float4*)&inb[(size_t)(v0 + r) * Cin + ci];
        if (XFORM) {
            val.x = fmaxf(val.x * sc[ci + 0] + sh[ci + 0], 0.0f);
            val.y = fmaxf(val.y * sc[ci + 1] + sh[ci + 1], 0.0f);
            val.z = fmaxf(val.z * sc[ci + 2] + sh[ci + 2], 0.0f);
            val.w = fmaxf(val.w * sc[ci + 3] + sh[ci + 3], 0.0f);
        }
        A_s[ci + 0][r ^ ((ci + 0) & 28)] = val.x;
        A_s[ci + 1][r ^ ((ci + 1) & 28)] = val.y;
        A_s[ci + 2][r ^ ((ci + 2) & 28)] = val.z;
        A_s[ci + 3][r ^ ((ci + 3) & 28)] = val.w;
    }
    __syncthreads();
    int c = t % CT;
    int r0 = (t / CT) * RPT;
    float acc[RPT][J];
    #pragma unroll
    for (int r = 0; r < RPT; r++)
        #pragma unroll
        for (int j = 0; j < J; j++) acc[r][j] = 0.0f;
    #pragma unroll 4
    for (int ci = 0; ci < Cin; ci++) {
        int sw = ci & 28;
        float w[J];
        #pragma unroll
        for (int j = 0; j < J; j++) w[j] = W13[(size_t)ci * Cout + c + CT * j];
        #pragma unroll
        for (int k = 0; k < RPT / 4; k++) {
            float4 a4 = *(const float4*)&A_s[ci][(r0 + 4 * k) ^ sw];
            #pragma unroll
            for (int j = 0; j < J; j++) {
                acc[4 * k + 0][j] += a4.x * w[j];
                acc[4 * k + 1][j] += a4.y * w[j];
                acc[4 * k + 2][j] += a4.z * w[j];
                acc[4 * k + 3][j] += a4.w * w[j];
            }
        }
    }
    float* ob = outp + (size_t)b * NPTS * Cout;
    float bs[J];
    #pragma unroll
    for (int j = 0; j < J; j++) bs[j] = bias[c + CT * j];
    #pragma unroll
    for (int r = 0; r < RPT; r++) {
        int row = v0 + r0 + r;
        if (row < nv) {
            #pragma unroll
            for (int j = 0; j < J; j++)
                ob[(size_t)row * Cout + c + CT * j] = acc[r][j] + bs[j];
        }
    }
}

// ---------- off-center: gather pair-rows, MAC with W from L2, scatter-add ----------
// One 64-pair chunk per block (atomics drain overlapped across exiting blocks);
// no W_s -> LDS 17.7KB -> ~6 blocks/CU vs 3-4; single gather barrier.
template <int Cin, int Cout, bool XFORM>
__global__ __launch_bounds__(256, 4) void conv_off(
    const float* __restrict__ in, float* __restrict__ outp,
    const float* __restrict__ W, const float* __restrict__ sc,
    const float* __restrict__ sh, const unsigned* __restrict__ pairs,
    const int* __restrict__ paircnt) {
    constexpr int BR  = PPB;
    constexpr int CT  = (Cout < 64) ? Cout : 64;
    constexpr int RG  = 256 / CT;
    constexpr int RPT = BR / RG;
    constexpr int J   = Cout / CT;
    int bk = blockIdx.y;            // b*27 + ko
    int ko = bk % 27;
    int b  = bk / 27;
    int cnt = paircnt[bk * PCS];
    if (cnt > CAP) cnt = CAP;
    int start = blockIdx.x * BR;
    if (start >= cnt) return;
    int nActive = cnt - start; if (nActive > BR) nActive = BR;
    __shared__ __align__(16) float A_s[Cin][BR + 4];
    __shared__ unsigned pr_s[BR];
    int t = threadIdx.x;
    const float* Wk = W + (size_t)ko * Cin * Cout;
    const unsigned* pb = pairs + (size_t)bk * CAP + start;
    if (t < BR) pr_s[t] = pb[t];
    __syncthreads();
    const float* inb = in + (size_t)b * NPTS * Cin;
    for (int i4 = t; i4 < BR * Cin / 4; i4 += 256) {
        int lin = i4 * 4;
        int r = lin / Cin, ci = lin % Cin;
        int vin = (int)(pr_s[r] & 0xffffu);
        float4 val = *(const float4*)&inb[(size_t)vin * Cin + ci];
        if (XFORM) {
            val.x = fmaxf(val.x * sc[ci + 0] + sh[ci + 0], 0.0f);
            val.y = fmaxf(val.y * sc[ci + 1] + sh[ci + 1], 0.0f);
            val.z = fmaxf(val.z * sc[ci + 2] + sh[ci + 2], 0.0f);
            val.w = fmaxf(val.w * sc[ci + 3] + sh[ci + 3], 0.0f);
        }
        A_s[ci + 0][r ^ ((ci + 0) & 28)] = val.x;
        A_s[ci + 1][r ^ ((ci + 1) & 28)] = val.y;
        A_s[ci + 2][r ^ ((ci + 2) & 28)] = val.z;
        A_s[ci + 3][r ^ ((ci + 3) & 28)] = val.w;
    }
    __syncthreads();
    int c = t % CT;
    int r0 = (t / CT) * RPT;
    float acc[RPT][J];
    #pragma unroll
    for (int r = 0; r < RPT; r++)
        #pragma unroll
        for (int j = 0; j < J; j++) acc[r][j] = 0.0f;
    #pragma unroll 4
    for (int ci = 0; ci < Cin; ci++) {
        int sw = ci & 28;
        float w[J];
        #pragma unroll
        for (int j = 0; j < J; j++) w[j] = Wk[(size_t)ci * Cout + c + CT * j];
        #pragma unroll
        for (int k = 0; k < RPT / 4; k++) {
            float4 a4 = *(const float4*)&A_s[ci][(r0 + 4 * k) ^ sw];
            #pragma unroll
            for (int j = 0; j < J; j++) {
                acc[4 * k + 0][j] += a4.x * w[j];
                acc[4 * k + 1][j] += a4.y * w[j];
                acc[4 * k + 2][j] += a4.z * w[j];
                acc[4 * k + 3][j] += a4.w * w[j];
            }
        }
    }
    float* ob = outp + (size_t)b * NPTS * Cout;
    #pragma unroll
    for (int r = 0; r < RPT; r++) {
        if (r0 + r < nActive) {
            int vout = (int)(pr_s[r0 + r] >> 16);
            #pragma unroll
            for (int j = 0; j < J; j++)
                atomicAdd(&ob[(size_t)vout * Cout + c + CT * j], acc[r][j]);
        }
    }
}

// ---------- BN stats: per-channel sum and sumsq over valid voxels ----------
template <int C>
__global__ void bn_stats(const float* __restrict__ h, const int* __restrict__ nvox,
                         float* __restrict__ sums) {
    constexpr int RPB = 256 / C;
    int b = blockIdx.y;
    int nv = nvox[b];
    int tid = threadIdx.x;
    int c = tid % C;
    int r = tid / C;
    float s0 = 0.0f, s1 = 0.0f;
    for (int v = blockIdx.x * RPB + r; v < nv; v += gridDim.x * RPB) {
        float x = h[((size_t)b * NPTS + v) * C + c];
        s0 += x;
        s1 += x * x;
    }
    __shared__ float l0[256], l1[256];
    l0[tid] = s0; l1[tid] = s1;
    __syncthreads();
    for (int s = 128; s >= C; s >>= 1) {
        if (tid < s) { l0[tid] += l0[tid + s]; l1[tid] += l1[tid + s]; }
        __syncthreads();
    }
    if (tid < C) {
        atomicAdd(&sums[c], l0[tid]);
        atomicAdd(&sums[C + c], l1[tid]);
    }
}

template <int C>
__global__ void bn_finalize(const float* __restrict__ sums, const int* __restrict__ nvox,
                            const float* __restrict__ g, const float* __restrict__ be,
                            float* __restrict__ scale, float* __restrict__ shift) {
    int c = threadIdx.x;
    if (c >= C) return;
    float n = 0.0f;
    for (int b = 0; b < NBATCH; b++) n += (float)nvox[b];
    n = fmaxf(n, 1.0f);
    float mean = sums[c] / n;
    float var = sums[C + c] / n - mean * mean;
    float a = g[c] * rsqrtf(var + 1e-5f);
    scale[c] = a;
    shift[c] = be[c] - mean * a;
}

// ---------- fused BN3 + ReLU + gather to points + mask (float4 vectorized) ----------
__global__ void out_gather(const float* __restrict__ h3, const int* __restrict__ inv,
                           const float* __restrict__ mask, const float* __restrict__ sc,
                           const float* __restrict__ sh, float* __restrict__ out) {
    int b = blockIdx.y;
    int i = blockIdx.x * blockDim.x + threadIdx.x; // over NPTS*32
    int p = i >> 5;
    int c4 = (i & 31) * 4;
    size_t gi = (size_t)b * NPTS + p;
    int v = inv[gi];
    float m = mask[gi];
    float4 x = *(const float4*)&h3[((size_t)b * NPTS + v) * 128 + c4];
    float4 s = *(const float4*)&sc[c4];
    float4 h = *(const float4*)&sh[c4];
    float4 o;
    o.x = fmaxf(x.x * s.x + h.x, 0.0f) * m;
    o.y = fmaxf(x.y * s.y + h.y, 0.0f) * m;
    o.z = fmaxf(x.z * s.z + h.z, 0.0f) * m;
    o.w = fmaxf(x.w * s.w + h.w, 0.0f) * m;
    *(float4*)&out[gi * 128 + c4] = o;
}

extern "C" void kernel_launch(void* const* d_in, const int* in_sizes, int n_in,
                              void* d_out, int out_size, void* d_ws, size_t ws_size,
                              hipStream_t stream) {
    const float* xyz  = (const float*)d_in[0];
    const float* feat = (const float*)d_in[1];
    const float* mask = (const float*)d_in[2];
    const float* W1 = (const float*)d_in[3];
    const float* b1 = (const float*)d_in[4];
    const float* g1 = (const float*)d_in[5];
    const float* be1 = (const float*)d_in[6];
    const float* W2 = (const float*)d_in[7];
    const float* b2 = (const float*)d_in[8];
    const float* g2 = (const float*)d_in[9];
    const float* be2 = (const float*)d_in[10];
    const float* W3 = (const float*)d_in[11];
    const float* b3 = (const float*)d_in[12];
    const float* g3 = (const float*)d_in[13];
    const float* be3 = (const float*)d_in[14];
    float* out = (float*)d_out;

    char* ws = (char*)d_ws;
    size_t off = 0;
    auto alloc = [&](size_t bytes) {
        void* p = ws + off;
        off += (bytes + 255) & ~(size_t)255;
        return p;
    };
    int*      hashk   = (int*)alloc((size_t)NBATCH * TSIZE * 4);
    int*      hashv   = (int*)alloc((size_t)NBATCH * TSIZE * 4);
    int*      scnt    = (int*)alloc((size_t)NBATCH * TSIZE * 4);
    int*      nvox    = (int*)alloc(NBATCH * 4);
    int*      origin  = (int*)alloc(16);
    int*      pslot   = (int*)alloc((size_t)NBATCH * NPTS * 4);
    int*      voxcode = (int*)alloc((size_t)NBATCH * NPTS * 4);
    int*      vnpts   = (int*)alloc((size_t)NBATCH * NPTS * 4);
    int*      inv     = (int*)alloc((size_t)NBATCH * NPTS * 4);
    float*    cntf    = (float*)alloc((size_t)NBATCH * NPTS * 4);
    unsigned* pairs   = (unsigned*)alloc((size_t)NBATCH * 27 * CAP * 4);
    int*      paircnt = (int*)alloc((size_t)NBATCH * 27 * PCS * 4);
    unsigned* bitmap  = (unsigned*)alloc((size_t)NBATCH * BMW * 4);
    float*    bnsums  = (float*)alloc(256 * 4);
    float*    bnscale = (float*)alloc(128 * 4);
    float*    bnshift = (float*)alloc(128 * 4);
    float*    A       = (float*)alloc((size_t)NBATCH * NPTS * 64 * 4);  // vfeat(16) then h2(64)
    float*    Bb      = (float*)alloc((size_t)NBATCH * NPTS * 128 * 4); // h1(32) then h3(128)

    // ---- zero / sentinel inits (ws is poisoned each call) ----
    hipMemsetAsync(hashk, 0xFF, (size_t)NBATCH * TSIZE * 4, stream); // keys = -1
    hipMemsetAsync(scnt, 0, (size_t)NBATCH * TSIZE * 4, stream);
    hipMemsetAsync(nvox, 0, NBATCH * 4, stream);
    hipMemsetAsync(cntf, 0, (size_t)NBATCH * NPTS * 4, stream);
    hipMemsetAsync(A, 0, (size_t)NBATCH * NPTS * 16 * 4, stream);    // fsum region
    hipMemsetAsync(paircnt, 0, (size_t)NBATCH * 27 * PCS * 4, stream);
    hipMemsetAsync(bitmap, 0, (size_t)NBATCH * BMW * 4, stream);
    init_origin<<<1, 64, 0, stream>>>(origin);

    // ---- voxelization ----
    minred<<<512, 256, 0, stream>>>(xyz, origin);
    build_codes<<<dim3(NPTS / 256, NBATCH), 256, 0, stream>>>(xyz, origin, pslot, hashk, scnt);
    assign_ids<<<dim3(TSIZE / 256, NBATCH), 256, 0, stream>>>(hashk, hashv, nvox, voxcode,
                                                              bitmap, scnt, vnpts);
    point_pass<<<dim3(NPTS / 256, NBATCH), 256, 0, stream>>>(pslot, scnt, hashv, feat, mask,
                                                             inv, cntf, A);
    vfeat_div<<<dim3(NPTS / 256, NBATCH), 256, 0, stream>>>(A, cntf, vnpts, nvox);

    // ---- rulebook (shared by all 3 layers): thread per voxel, bitmap-probed ----
    build_pairs<<<dim3(NPTS / 256, NBATCH), 256, 0, stream>>>(hashk, hashv, voxcode,
                                                              nvox, bitmap, pairs, paircnt);

    dim3 cgrid(NPTS / 64, NBATCH);
    dim3 ogrid(CAP / PPB, NBATCH * 27);

    // ---- layer 1: 16 -> 32 (no input transform) ----
    conv_center<16, 32, false><<<cgrid, 256, 0, stream>>>(A, Bb, W1 + 13 * 16 * 32, b1,
                                                          nullptr, nullptr, nvox);
    conv_off<16, 32, false><<<ogrid, 256, 0, stream>>>(A, Bb, W1, nullptr, nullptr,
                                                       pairs, paircnt);
    hipMemsetAsync(bnsums, 0, 256 * 4, stream);
    bn_stats<32><<<dim3(64, NBATCH), 256, 0, stream>>>(Bb, nvox, bnsums);
    bn_finalize<32><<<1, 128, 0, stream>>>(bnsums, nvox, g1, be1, bnscale, bnshift);

    // ---- layer 2: 32 -> 64 (fused BN1+ReLU on gather) ----
    conv_center<32, 64, true><<<cgrid, 256, 0, stream>>>(Bb, A, W2 + 13 * 32 * 64, b2,
                                                         bnscale, bnshift, nvox);
    conv_off<32, 64, true><<<ogrid, 256, 0, stream>>>(Bb, A, W2, bnscale, bnshift,
                                                      pairs, paircnt);
    hipMemsetAsync(bnsums, 0, 256 * 4, stream);
    bn_stats<64><<<dim3(64, NBATCH), 256, 0, stream>>>(A, nvox, bnsums);
    bn_finalize<64><<<1, 128, 0, stream>>>(bnsums, nvox, g2, be2, bnscale, bnshift);

    // ---- layer 3: 64 -> 128 (fused BN2+ReLU on gather) ----
    conv_center<64, 128, true><<<cgrid, 256, 0, stream>>>(A, Bb, W3 + 13 * 64 * 128, b3,
                                                          bnscale, bnshift, nvox);
    conv_off<64, 128, true><<<ogrid, 256, 0, stream>>>(A, Bb, W3, bnscale, bnshift,
                                                       pairs, paircnt);
    hipMemsetAsync(bnsums, 0, 256 * 4, stream);
    bn_stats<128><<<dim3(64, NBATCH), 256, 0, stream>>>(Bb, nvox, bnsums);
    bn_finalize<128><<<1, 128, 0, stream>>>(bnsums, nvox, g3, be3, bnscale, bnshift);

    // ---- fused BN3 + ReLU + gather + mask ----
    out_gather<<<dim3(NPTS * 32 / 256, NBATCH), 256, 0, stream>>>(Bb, inv, mask, bnscale,
                                                                  bnshift, out);
}